// Round 5
// baseline (207.704 us; speedup 1.0000x reference)
//
#include <hip/hip_runtime.h>

// PAFA loss, MI355X. N=262144 rows, D=256 cols, P=512 patients.
//   within  = sum||x||^2 - sum_p cnt_p*||c_p||^2
//   between = P*sum||c_p||^2 - ||sum_p c_p||^2   (T = sum_p c_p, TT = ||T||^2)
//   gpal    = S2/P - TT/P^2
//   loss    = 0.1*within/(between+1e-6) + 0.1*gpal
//
// Pipeline: hist (per-block LDS hist -> bh[pat][blk])
//           scan (per-patient prefix across blocks in-place + patient scan)
//           scatter (NO atomics beyond LDS cursors; bases fully precomputed)
//           main (one block/patient, contiguous per-wave idx chunks,
//                 readlane row broadcast, scalar-addressed gathers; fused final)

#define DIMS 256
#define NPAT 512
#define HB 64        // hist/scatter blocks
#define HT 1024      // threads per hist/scatter block

// ws layout (bytes):
//   0      counts  u32[512]
//   2048   starts  u32[512]
//   4096   scalars f32[4] = {SumSq, S1, S2, -}
//   4352   done    u32
//   4608   T       f32[256]
//   8192   bh      u32[512*64]  [pat][blk] (128 KB), becomes exclusive prefix
//   139264 idx     u32[N]       (1 MB)

extern "C" __global__ void __launch_bounds__(HT)
k_hist(const int* __restrict__ pids, int N, unsigned* __restrict__ bh)
{
    __shared__ unsigned h[NPAT];
    const int t = threadIdx.x;
    if (t < NPAT) h[t] = 0u;
    __syncthreads();

    const int r = (blockIdx.x * HT + t) * 4;   // N = HB*HT*4 = 262144 exactly
    if (r + 3 < N) {
        const int4 p4 = *reinterpret_cast<const int4*>(pids + r);
        atomicAdd(&h[p4.x], 1u);
        atomicAdd(&h[p4.y], 1u);
        atomicAdd(&h[p4.z], 1u);
        atomicAdd(&h[p4.w], 1u);
    } else {
        for (int k = 0; k < 4; ++k)
            if (r + k < N) atomicAdd(&h[pids[r + k]], 1u);
    }
    __syncthreads();
    if (t < NPAT) bh[t * HB + blockIdx.x] = h[t];
}

// One block, 512 threads. Thread t: serial exclusive scan of bh[t][0..63]
// (in place), total -> counts[t]; then Hillis-Steele over patients -> starts.
extern "C" __global__ void __launch_bounds__(NPAT)
k_scan(unsigned* __restrict__ bh, unsigned* __restrict__ counts,
       unsigned* __restrict__ starts, float* __restrict__ scalars,
       float* __restrict__ T, unsigned* __restrict__ done)
{
    __shared__ unsigned tmp[NPAT];
    const int t = threadIdx.x;

    uint4* row = reinterpret_cast<uint4*>(bh + t * HB);
    unsigned run = 0u;
    #pragma unroll
    for (int k = 0; k < HB / 4; ++k) {
        const uint4 v = row[k];
        uint4 e;
        e.x = run;
        e.y = e.x + v.x;
        e.z = e.y + v.y;
        e.w = e.z + v.z;
        run = e.w + v.w;
        row[k] = e;
    }
    counts[t] = run;
    tmp[t] = run;
    __syncthreads();
    for (int off = 1; off < NPAT; off <<= 1) {
        const unsigned v = (t >= off) ? tmp[t - off] : 0u;
        __syncthreads();
        tmp[t] += v;
        __syncthreads();
    }
    starts[t] = tmp[t] - run;   // exclusive

    if (t < 4)    scalars[t] = 0.0f;
    if (t == 4)   *done      = 0u;
    if (t < DIMS) T[t]       = 0.0f;
}

// Placement: bases fully precomputed -> LDS cursors only, no global atomics.
extern "C" __global__ void __launch_bounds__(HT)
k_scatter(const int* __restrict__ pids, int N,
          const unsigned* __restrict__ bh, const unsigned* __restrict__ starts,
          unsigned* __restrict__ idx)
{
    __shared__ unsigned basec[NPAT];
    const int t = threadIdx.x;
    if (t < NPAT) basec[t] = starts[t] + bh[t * HB + blockIdx.x];
    __syncthreads();

    const int r = (blockIdx.x * HT + t) * 4;
    if (r + 3 < N) {
        const int4 p4 = *reinterpret_cast<const int4*>(pids + r);
        idx[atomicAdd(&basec[p4.x], 1u)] = (unsigned)(r + 0);
        idx[atomicAdd(&basec[p4.y], 1u)] = (unsigned)(r + 1);
        idx[atomicAdd(&basec[p4.z], 1u)] = (unsigned)(r + 2);
        idx[atomicAdd(&basec[p4.w], 1u)] = (unsigned)(r + 3);
    } else {
        for (int k = 0; k < 4; ++k)
            if (r + k < N)
                idx[atomicAdd(&basec[pids[r + k]], 1u)] = (unsigned)(r + k);
    }
}

// One block per patient: 8 waves; wave w owns a contiguous 1/8 chunk of the
// patient's sorted rows. Lane l loads idx[g+l] (coalesced), row ids broadcast
// via readlane -> scalar addresses, gathers independent (deep MLP).
// Last-done block computes the final scalar loss (fused k_final).
extern "C" __global__ void __launch_bounds__(512)
k_main(const float* __restrict__ feats, const unsigned* __restrict__ idx,
       const unsigned* __restrict__ counts, const unsigned* __restrict__ starts,
       float* __restrict__ T, float* __restrict__ scalars,
       unsigned* __restrict__ done, const int* __restrict__ nump,
       float* __restrict__ out)
{
    __shared__ float part[8][DIMS];
    __shared__ float sred[8];
    __shared__ float cred[4];
    __shared__ float red[8];
    __shared__ unsigned lastflag;

    const int p    = blockIdx.x;
    const int lane = threadIdx.x & 63;
    const int w    = threadIdx.x >> 6;        // wave 0..7
    const unsigned start = starts[p];
    const unsigned cnt   = counts[p];
    const unsigned base  = lane * 4;

    float ax = 0.f, ay = 0.f, az = 0.f, aw = 0.f;
    float ssq = 0.f;

    const unsigned cbeg = start + ((cnt * (unsigned)w) >> 3);
    const unsigned cend = start + ((cnt * (unsigned)(w + 1)) >> 3);

    for (unsigned g = cbeg; g < cend; g += 64) {
        const unsigned nr = (cend - g < 64u) ? (cend - g) : 64u;
        const unsigned myrow = idx[g + lane];   // <=63 past patient end: value unused
        if (nr == 64u) {
            #pragma unroll
            for (int k0 = 0; k0 < 64; k0 += 8) {
                float4 v[8];
                #pragma unroll
                for (int k = 0; k < 8; ++k) {
                    const unsigned row =
                        (unsigned)__builtin_amdgcn_readlane((int)myrow, k0 + k);
                    v[k] = *reinterpret_cast<const float4*>(
                        feats + (size_t)row * DIMS + base);
                }
                #pragma unroll
                for (int k = 0; k < 8; ++k) {
                    ax += v[k].x; ay += v[k].y; az += v[k].z; aw += v[k].w;
                    ssq += v[k].x*v[k].x + v[k].y*v[k].y
                         + v[k].z*v[k].z + v[k].w*v[k].w;
                }
            }
        } else {
            for (unsigned k = 0; k < nr; ++k) {
                const unsigned row =
                    (unsigned)__builtin_amdgcn_readlane((int)myrow, (int)k);
                const float4 v = *reinterpret_cast<const float4*>(
                    feats + (size_t)row * DIMS + base);
                ax += v.x; ay += v.y; az += v.z; aw += v.w;
                ssq += v.x*v.x + v.y*v.y + v.z*v.z + v.w*v.w;
            }
        }
    }

    part[w][base + 0] = ax;
    part[w][base + 1] = ay;
    part[w][base + 2] = az;
    part[w][base + 3] = aw;
    for (int off = 32; off; off >>= 1) ssq += __shfl_down(ssq, off, 64);
    if (lane == 0) sred[w] = ssq;
    __syncthreads();

    const int d = threadIdx.x;
    if (d < DIMS) {
        float s = 0.f;
        #pragma unroll
        for (int ww = 0; ww < 8; ++ww) s += part[ww][d];
        const float cntf = fmaxf((float)cnt, 1.0f);
        const float c = s / cntf;
        atomicAdd(&T[d], c);
        float csq = c * c;
        for (int off = 32; off; off >>= 1) csq += __shfl_down(csq, off, 64);
        if ((d & 63) == 0) cred[d >> 6] = csq;
    }
    __syncthreads();

    if (threadIdx.x == 0) {
        const float s2p = cred[0] + cred[1] + cred[2] + cred[3];
        const float cntf = fmaxf((float)cnt, 1.0f);
        atomicAdd(&scalars[2], s2p);          // S2 += ||c_p||^2
        atomicAdd(&scalars[1], cntf * s2p);   // S1 += cnt_p * ||c_p||^2
        float sq = 0.f;
        #pragma unroll
        for (int ww = 0; ww < 8; ++ww) sq += sred[ww];
        atomicAdd(&scalars[0], sq);           // SumSq
    }

    // ---- fused final: last block to finish computes the loss ----
    __threadfence();
    if (threadIdx.x == 0) {
        const unsigned prev = atomicAdd(done, 1u);
        lastflag = (prev == (unsigned)(gridDim.x - 1)) ? 1u : 0u;
    }
    __syncthreads();
    if (lastflag) {
        float tt = 0.f;
        if (d < DIMS) {
            const float tv = __hip_atomic_load(&T[d], __ATOMIC_RELAXED,
                                               __HIP_MEMORY_SCOPE_AGENT);
            tt = tv * tv;
        }
        for (int off = 32; off; off >>= 1) tt += __shfl_down(tt, off, 64);
        if ((d & 63) == 0) red[d >> 6] = tt;
        __syncthreads();
        if (d == 0) {
            const double TT = (double)red[0] + red[1] + red[2] + red[3]
                            + red[4] + red[5] + red[6] + red[7];
            const double SumSq = (double)__hip_atomic_load(&scalars[0],
                __ATOMIC_RELAXED, __HIP_MEMORY_SCOPE_AGENT);
            const double S1 = (double)__hip_atomic_load(&scalars[1],
                __ATOMIC_RELAXED, __HIP_MEMORY_SCOPE_AGENT);
            const double S2 = (double)__hip_atomic_load(&scalars[2],
                __ATOMIC_RELAXED, __HIP_MEMORY_SCOPE_AGENT);
            const double Pd = (double)(*nump);
            const double within  = SumSq - S1;
            const double between = Pd * S2 - TT;
            const double pcsl = within / (between + 1e-6);
            const double gpal = S2 / Pd - TT / (Pd * Pd);
            out[0] = (float)(0.1 * pcsl + 0.1 * gpal);
        }
    }
}

extern "C" void kernel_launch(void* const* d_in, const int* in_sizes, int n_in,
                              void* d_out, int out_size, void* d_ws, size_t ws_size,
                              hipStream_t stream)
{
    const float* feats = (const float*)d_in[0];
    const int*   pids  = (const int*)d_in[1];
    const int*   nump  = (const int*)d_in[2];
    float*       out   = (float*)d_out;

    const int N = in_sizes[0] / DIMS;

    char* ws = (char*)d_ws;
    unsigned* counts  = (unsigned*)(ws);
    unsigned* starts  = (unsigned*)(ws + 2048);
    float*    scalars = (float*)(ws + 4096);
    unsigned* done    = (unsigned*)(ws + 4352);
    float*    T       = (float*)(ws + 4608);
    unsigned* bh      = (unsigned*)(ws + 8192);
    unsigned* idx     = (unsigned*)(ws + 139264);

    k_hist   <<<dim3(HB),   dim3(HT),   0, stream>>>(pids, N, bh);
    k_scan   <<<dim3(1),    dim3(NPAT), 0, stream>>>(bh, counts, starts,
                                                     scalars, T, done);
    k_scatter<<<dim3(HB),   dim3(HT),   0, stream>>>(pids, N, bh, starts, idx);
    k_main   <<<dim3(NPAT), dim3(512),  0, stream>>>(feats, idx, counts, starts,
                                                     T, scalars, done, nump, out);
}

// Round 6
// 181.378 us; speedup vs baseline: 1.1451x; 1.1451x over previous
//
#include <hip/hip_runtime.h>

// PAFA loss, MI355X. N=262144 rows, D=256 cols, P=512 patients.
//   within  = sum||x||^2 - sum_p cnt_p*||c_p||^2
//   between = P*sum||c_p||^2 - ||sum_p c_p||^2   (T = sum_p c_p, TT = ||T||^2)
//   gpal    = S2/P - TT/P^2
//   loss    = 0.1*within/(between+1e-6) + 0.1*gpal
//
// Pipeline: hist (per-block LDS hist -> bh[pat][blk])
//           scan (per-patient prefix across blocks in-place + patient scan)
//           scatter (no global atomics; bases precomputed from bh prefix)
//           main (one block/patient, per-lane VGPR gather addresses,
//                 8 float4 loads in flight per wave; fused final reduce)
//
// R5 lesson: do NOT scalarize the gather addresses (readlane->SGPR). The
// compiler then register-minimizes to a serial load-use chain (VGPR=36,
// zero MLP, 290us). Per-lane VGPR addresses keep 8 loads in flight.

#define DIMS 256
#define NPAT 512
#define HB 64        // hist/scatter blocks
#define HT 1024      // threads per hist/scatter block

// ws layout (bytes):
//   0      counts  u32[512]
//   2048   starts  u32[512]
//   4096   scalars f32[4] = {SumSq, S1, S2, -}
//   4352   done    u32
//   4608   T       f32[256]
//   8192   bh      u32[512*64]  [pat][blk] (128 KB), becomes exclusive prefix
//   139264 idx     u32[N]       (1 MB)

extern "C" __global__ void __launch_bounds__(HT)
k_hist(const int* __restrict__ pids, int N, unsigned* __restrict__ bh)
{
    __shared__ unsigned h[NPAT];
    const int t = threadIdx.x;
    if (t < NPAT) h[t] = 0u;
    __syncthreads();

    const int r = (blockIdx.x * HT + t) * 4;   // N = HB*HT*4 = 262144 exactly
    if (r + 3 < N) {
        const int4 p4 = *reinterpret_cast<const int4*>(pids + r);
        atomicAdd(&h[p4.x], 1u);
        atomicAdd(&h[p4.y], 1u);
        atomicAdd(&h[p4.z], 1u);
        atomicAdd(&h[p4.w], 1u);
    } else {
        for (int k = 0; k < 4; ++k)
            if (r + k < N) atomicAdd(&h[pids[r + k]], 1u);
    }
    __syncthreads();
    if (t < NPAT) bh[t * HB + blockIdx.x] = h[t];
}

// One block, 512 threads. Thread t: serial exclusive scan of bh[t][0..63]
// (in place), total -> counts[t]; then Hillis-Steele over patients -> starts.
extern "C" __global__ void __launch_bounds__(NPAT)
k_scan(unsigned* __restrict__ bh, unsigned* __restrict__ counts,
       unsigned* __restrict__ starts, float* __restrict__ scalars,
       float* __restrict__ T, unsigned* __restrict__ done)
{
    __shared__ unsigned tmp[NPAT];
    const int t = threadIdx.x;

    uint4* row = reinterpret_cast<uint4*>(bh + t * HB);
    unsigned run = 0u;
    #pragma unroll
    for (int k = 0; k < HB / 4; ++k) {
        const uint4 v = row[k];
        uint4 e;
        e.x = run;
        e.y = e.x + v.x;
        e.z = e.y + v.y;
        e.w = e.z + v.z;
        run = e.w + v.w;
        row[k] = e;
    }
    counts[t] = run;
    tmp[t] = run;
    __syncthreads();
    for (int off = 1; off < NPAT; off <<= 1) {
        const unsigned v = (t >= off) ? tmp[t - off] : 0u;
        __syncthreads();
        tmp[t] += v;
        __syncthreads();
    }
    starts[t] = tmp[t] - run;   // exclusive

    if (t < 4)    scalars[t] = 0.0f;
    if (t == 4)   *done      = 0u;
    if (t < DIMS) T[t]       = 0.0f;
}

// Placement: bases fully precomputed -> LDS cursors only, no global atomics.
extern "C" __global__ void __launch_bounds__(HT)
k_scatter(const int* __restrict__ pids, int N,
          const unsigned* __restrict__ bh, const unsigned* __restrict__ starts,
          unsigned* __restrict__ idx)
{
    __shared__ unsigned basec[NPAT];
    const int t = threadIdx.x;
    if (t < NPAT) basec[t] = starts[t] + bh[t * HB + blockIdx.x];
    __syncthreads();

    const int r = (blockIdx.x * HT + t) * 4;
    if (r + 3 < N) {
        const int4 p4 = *reinterpret_cast<const int4*>(pids + r);
        idx[atomicAdd(&basec[p4.x], 1u)] = (unsigned)(r + 0);
        idx[atomicAdd(&basec[p4.y], 1u)] = (unsigned)(r + 1);
        idx[atomicAdd(&basec[p4.z], 1u)] = (unsigned)(r + 2);
        idx[atomicAdd(&basec[p4.w], 1u)] = (unsigned)(r + 3);
    } else {
        for (int k = 0; k < 4; ++k)
            if (r + k < N)
                idx[atomicAdd(&basec[pids[r + k]], 1u)] = (unsigned)(r + k);
    }
}

// One block per patient: 8 waves, each wave reads whole rows (float4/lane),
// 8 rows in flight per wave via per-lane VGPR addresses (proven 77us form).
// Last-done block computes the final scalar loss (fused k_final).
extern "C" __global__ void __launch_bounds__(512)
k_main(const float* __restrict__ feats, const unsigned* __restrict__ idx,
       const unsigned* __restrict__ counts, const unsigned* __restrict__ starts,
       float* __restrict__ T, float* __restrict__ scalars,
       unsigned* __restrict__ done, const int* __restrict__ nump,
       float* __restrict__ out)
{
    __shared__ float part[8][DIMS];
    __shared__ float sred[8];
    __shared__ float cred[4];
    __shared__ float red[8];
    __shared__ unsigned lastflag;

    const int p    = blockIdx.x;
    const int lane = threadIdx.x & 63;
    const int w    = threadIdx.x >> 6;        // wave 0..7
    const unsigned start = starts[p];
    const unsigned cnt   = counts[p];
    const unsigned base  = lane * 4;

    float ax = 0.f, ay = 0.f, az = 0.f, aw = 0.f;
    float ssq = 0.f;

    unsigned j = (unsigned)w;
    for (; j + 56 < cnt; j += 64) {
        unsigned rr[8];
        #pragma unroll
        for (int k = 0; k < 8; ++k) rr[k] = idx[start + j + 8 * k];
        float4 v[8];
        #pragma unroll
        for (int k = 0; k < 8; ++k)
            v[k] = *reinterpret_cast<const float4*>(feats + (size_t)rr[k] * DIMS + base);
        #pragma unroll
        for (int k = 0; k < 8; ++k) {
            ax += v[k].x; ay += v[k].y; az += v[k].z; aw += v[k].w;
            ssq += v[k].x*v[k].x + v[k].y*v[k].y + v[k].z*v[k].z + v[k].w*v[k].w;
        }
    }
    for (; j < cnt; j += 8) {
        const unsigned row = idx[start + j];
        const float4 v = *reinterpret_cast<const float4*>(feats + (size_t)row * DIMS + base);
        ax += v.x; ay += v.y; az += v.z; aw += v.w;
        ssq += v.x*v.x + v.y*v.y + v.z*v.z + v.w*v.w;
    }

    part[w][base + 0] = ax;
    part[w][base + 1] = ay;
    part[w][base + 2] = az;
    part[w][base + 3] = aw;
    for (int off = 32; off; off >>= 1) ssq += __shfl_down(ssq, off, 64);
    if (lane == 0) sred[w] = ssq;
    __syncthreads();

    const int d = threadIdx.x;
    if (d < DIMS) {
        float s = 0.f;
        #pragma unroll
        for (int ww = 0; ww < 8; ++ww) s += part[ww][d];
        const float cntf = fmaxf((float)cnt, 1.0f);
        const float c = s / cntf;
        atomicAdd(&T[d], c);
        float csq = c * c;
        for (int off = 32; off; off >>= 1) csq += __shfl_down(csq, off, 64);
        if ((d & 63) == 0) cred[d >> 6] = csq;
    }
    __syncthreads();

    if (threadIdx.x == 0) {
        const float s2p = cred[0] + cred[1] + cred[2] + cred[3];
        const float cntf = fmaxf((float)cnt, 1.0f);
        atomicAdd(&scalars[2], s2p);          // S2 += ||c_p||^2
        atomicAdd(&scalars[1], cntf * s2p);   // S1 += cnt_p * ||c_p||^2
        float sq = 0.f;
        #pragma unroll
        for (int ww = 0; ww < 8; ++ww) sq += sred[ww];
        atomicAdd(&scalars[0], sq);           // SumSq
    }

    // ---- fused final: last block to finish computes the loss ----
    __threadfence();
    if (threadIdx.x == 0) {
        const unsigned prev = atomicAdd(done, 1u);
        lastflag = (prev == (unsigned)(gridDim.x - 1)) ? 1u : 0u;
    }
    __syncthreads();
    if (lastflag) {
        float tt = 0.f;
        if (d < DIMS) {
            const float tv = __hip_atomic_load(&T[d], __ATOMIC_RELAXED,
                                               __HIP_MEMORY_SCOPE_AGENT);
            tt = tv * tv;
        }
        for (int off = 32; off; off >>= 1) tt += __shfl_down(tt, off, 64);
        if ((d & 63) == 0) red[d >> 6] = tt;
        __syncthreads();
        if (d == 0) {
            const double TT = (double)red[0] + red[1] + red[2] + red[3]
                            + red[4] + red[5] + red[6] + red[7];
            const double SumSq = (double)__hip_atomic_load(&scalars[0],
                __ATOMIC_RELAXED, __HIP_MEMORY_SCOPE_AGENT);
            const double S1 = (double)__hip_atomic_load(&scalars[1],
                __ATOMIC_RELAXED, __HIP_MEMORY_SCOPE_AGENT);
            const double S2 = (double)__hip_atomic_load(&scalars[2],
                __ATOMIC_RELAXED, __HIP_MEMORY_SCOPE_AGENT);
            const double Pd = (double)(*nump);
            const double within  = SumSq - S1;
            const double between = Pd * S2 - TT;
            const double pcsl = within / (between + 1e-6);
            const double gpal = S2 / Pd - TT / (Pd * Pd);
            out[0] = (float)(0.1 * pcsl + 0.1 * gpal);
        }
    }
}

extern "C" void kernel_launch(void* const* d_in, const int* in_sizes, int n_in,
                              void* d_out, int out_size, void* d_ws, size_t ws_size,
                              hipStream_t stream)
{
    const float* feats = (const float*)d_in[0];
    const int*   pids  = (const int*)d_in[1];
    const int*   nump  = (const int*)d_in[2];
    float*       out   = (float*)d_out;

    const int N = in_sizes[0] / DIMS;

    char* ws = (char*)d_ws;
    unsigned* counts  = (unsigned*)(ws);
    unsigned* starts  = (unsigned*)(ws + 2048);
    float*    scalars = (float*)(ws + 4096);
    unsigned* done    = (unsigned*)(ws + 4352);
    float*    T       = (float*)(ws + 4608);
    unsigned* bh      = (unsigned*)(ws + 8192);
    unsigned* idx     = (unsigned*)(ws + 139264);

    k_hist   <<<dim3(HB),   dim3(HT),   0, stream>>>(pids, N, bh);
    k_scan   <<<dim3(1),    dim3(NPAT), 0, stream>>>(bh, counts, starts,
                                                     scalars, T, done);
    k_scatter<<<dim3(HB),   dim3(HT),   0, stream>>>(pids, N, bh, starts, idx);
    k_main   <<<dim3(NPAT), dim3(512),  0, stream>>>(feats, idx, counts, starts,
                                                     T, scalars, done, nump, out);
}

// Round 7
// 76.291 us; speedup vs baseline: 2.7225x; 2.3775x over previous
//
#include <hip/hip_runtime.h>

// PAFA loss, MI355X. N=262144 rows, D=256 cols, P=512 patients.
//   within  = sum||x||^2 - sum_p cnt_p*||c_p||^2
//   between = P*sum||c_p||^2 - ||sum_p c_p||^2   (T = sum_p c_p, TT = ||T||^2)
//   gpal    = S2/P - TT/P^2
//   loss    = 0.1*within/(between+1e-6) + 0.1*gpal
//
// Pipeline: hist -> scan (4-aligned patient segments) -> atomic-free scatter
//           -> main (512 blocks x 16 waves, TLP-driven latency hiding,
//                    uint4 row-id batches + 4 independent float4 gathers)
//           -> final (tiny).
//
// R5 lesson: never scalarize gather addresses (readlane) - compiler
//   register-minimizes to a serial chain (VGPR=36, 290us).
// R6 lesson: a fused double-precision tail perturbed regalloc of the hot
//   loop (VGPR=32, serialized loads, 255us). Keep k_main LEAN; rely on
//   TLP (32 waves/CU), not on the scheduler keeping 8 loads in flight.

#define DIMS 256
#define NPAT 512
#define HB 64        // hist/scatter blocks
#define HT 1024      // threads per hist/scatter block
#define MT 1024      // main threads per block
#define MW 16        // main waves per block

// ws layout (bytes):
//   0      counts  u32[512]
//   2048   starts  u32[512]   (4-aligned padded starts)
//   4096   scalars f32[4] = {SumSq, S1, S2, -}
//   4608   T       f32[256]
//   8192   bh      u32[512*64]  [pat][blk] (128 KB) -> exclusive prefix
//   139264 idx     u32[N + 4*NPAT]
extern "C" __global__ void __launch_bounds__(HT)
k_hist(const int* __restrict__ pids, int N, unsigned* __restrict__ bh)
{
    __shared__ unsigned h[NPAT];
    const int t = threadIdx.x;
    if (t < NPAT) h[t] = 0u;
    __syncthreads();

    const int r = (blockIdx.x * HT + t) * 4;   // N = HB*HT*4 = 262144 exactly
    if (r + 3 < N) {
        const int4 p4 = *reinterpret_cast<const int4*>(pids + r);
        atomicAdd(&h[p4.x], 1u);
        atomicAdd(&h[p4.y], 1u);
        atomicAdd(&h[p4.z], 1u);
        atomicAdd(&h[p4.w], 1u);
    } else {
        for (int k = 0; k < 4; ++k)
            if (r + k < N) atomicAdd(&h[pids[r + k]], 1u);
    }
    __syncthreads();
    if (t < NPAT) bh[t * HB + blockIdx.x] = h[t];
}

// One block, 512 threads. Thread t: in-place exclusive scan of bh[t][0..63],
// total -> counts[t]; then Hillis-Steele over PADDED counts -> 4-aligned starts.
extern "C" __global__ void __launch_bounds__(NPAT)
k_scan(unsigned* __restrict__ bh, unsigned* __restrict__ counts,
       unsigned* __restrict__ starts, float* __restrict__ scalars,
       float* __restrict__ T)
{
    __shared__ unsigned tmp[NPAT];
    const int t = threadIdx.x;

    uint4* row = reinterpret_cast<uint4*>(bh + t * HB);
    unsigned run = 0u;
    #pragma unroll
    for (int k = 0; k < HB / 4; ++k) {
        const uint4 v = row[k];
        uint4 e;
        e.x = run;
        e.y = e.x + v.x;
        e.z = e.y + v.y;
        e.w = e.z + v.z;
        run = e.w + v.w;
        row[k] = e;
    }
    counts[t] = run;
    const unsigned padded = (run + 3u) & ~3u;   // 4-aligned segment
    tmp[t] = padded;
    __syncthreads();
    for (int off = 1; off < NPAT; off <<= 1) {
        const unsigned v = (t >= off) ? tmp[t - off] : 0u;
        __syncthreads();
        tmp[t] += v;
        __syncthreads();
    }
    starts[t] = tmp[t] - padded;   // exclusive, 4-aligned

    if (t < 4)    scalars[t] = 0.0f;
    if (t < DIMS) T[t]       = 0.0f;
}

// Placement: bases fully precomputed -> LDS cursors only, no global atomics.
extern "C" __global__ void __launch_bounds__(HT)
k_scatter(const int* __restrict__ pids, int N,
          const unsigned* __restrict__ bh, const unsigned* __restrict__ starts,
          unsigned* __restrict__ idx)
{
    __shared__ unsigned basec[NPAT];
    const int t = threadIdx.x;
    if (t < NPAT) basec[t] = starts[t] + bh[t * HB + blockIdx.x];
    __syncthreads();

    const int r = (blockIdx.x * HT + t) * 4;
    if (r + 3 < N) {
        const int4 p4 = *reinterpret_cast<const int4*>(pids + r);
        idx[atomicAdd(&basec[p4.x], 1u)] = (unsigned)(r + 0);
        idx[atomicAdd(&basec[p4.y], 1u)] = (unsigned)(r + 1);
        idx[atomicAdd(&basec[p4.z], 1u)] = (unsigned)(r + 2);
        idx[atomicAdd(&basec[p4.w], 1u)] = (unsigned)(r + 3);
    } else {
        for (int k = 0; k < 4; ++k)
            if (r + k < N)
                idx[atomicAdd(&basec[pids[r + k]], 1u)] = (unsigned)(r + k);
    }
}

// One block per patient, 16 waves. Wave w handles 4-row batches b = w, w+16,...
// Per batch: one aligned uint4 row-id load (wave-uniform), then 4 independent
// per-lane float4 gathers. Latency hidden by 32 waves/CU TLP.
extern "C" __global__ void __launch_bounds__(MT, 4)
k_main(const float* __restrict__ feats, const unsigned* __restrict__ idx,
       const unsigned* __restrict__ counts, const unsigned* __restrict__ starts,
       float* __restrict__ T, float* __restrict__ scalars)
{
    __shared__ float part[MW][DIMS];   // 16 KB
    __shared__ float sred[MW];
    __shared__ float cred[4];

    const int p    = blockIdx.x;
    const int lane = threadIdx.x & 63;
    const int w    = threadIdx.x >> 6;        // wave 0..15
    const unsigned start = starts[p];
    const unsigned cnt   = counts[p];
    const unsigned base  = lane * 4;

    float ax = 0.f, ay = 0.f, az = 0.f, aw = 0.f;
    float ssq = 0.f;

    const unsigned nb = cnt >> 2;             // full 4-row batches
    for (unsigned b = (unsigned)w; b < nb; b += MW) {
        const uint4 cid = *reinterpret_cast<const uint4*>(idx + start + 4u * b);
        const float4 v0 = *reinterpret_cast<const float4*>(feats + (size_t)cid.x * DIMS + base);
        const float4 v1 = *reinterpret_cast<const float4*>(feats + (size_t)cid.y * DIMS + base);
        const float4 v2 = *reinterpret_cast<const float4*>(feats + (size_t)cid.z * DIMS + base);
        const float4 v3 = *reinterpret_cast<const float4*>(feats + (size_t)cid.w * DIMS + base);
        ax += v0.x + v1.x + v2.x + v3.x;
        ay += v0.y + v1.y + v2.y + v3.y;
        az += v0.z + v1.z + v2.z + v3.z;
        aw += v0.w + v1.w + v2.w + v3.w;
        ssq += v0.x*v0.x + v0.y*v0.y + v0.z*v0.z + v0.w*v0.w;
        ssq += v1.x*v1.x + v1.y*v1.y + v1.z*v1.z + v1.w*v1.w;
        ssq += v2.x*v2.x + v2.y*v2.y + v2.z*v2.z + v2.w*v2.w;
        ssq += v3.x*v3.x + v3.y*v3.y + v3.z*v3.z + v3.w*v3.w;
    }
    if (w == 0) {   // remainder rows (cnt & 3)
        for (unsigned r = nb * 4u; r < cnt; ++r) {
            const unsigned row = idx[start + r];
            const float4 v = *reinterpret_cast<const float4*>(feats + (size_t)row * DIMS + base);
            ax += v.x; ay += v.y; az += v.z; aw += v.w;
            ssq += v.x*v.x + v.y*v.y + v.z*v.z + v.w*v.w;
        }
    }

    part[w][base + 0] = ax;
    part[w][base + 1] = ay;
    part[w][base + 2] = az;
    part[w][base + 3] = aw;
    for (int off = 32; off; off >>= 1) ssq += __shfl_down(ssq, off, 64);
    if (lane == 0) sred[w] = ssq;
    __syncthreads();

    const int d = threadIdx.x;
    if (d < DIMS) {
        float s = 0.f;
        #pragma unroll
        for (int ww = 0; ww < MW; ++ww) s += part[ww][d];
        const float cntf = fmaxf((float)cnt, 1.0f);
        const float c = s / cntf;
        atomicAdd(&T[d], c);
        float csq = c * c;
        for (int off = 32; off; off >>= 1) csq += __shfl_down(csq, off, 64);
        if ((d & 63) == 0) cred[d >> 6] = csq;
    }
    __syncthreads();

    if (threadIdx.x == 0) {
        const float s2p = cred[0] + cred[1] + cred[2] + cred[3];
        const float cntf = fmaxf((float)cnt, 1.0f);
        atomicAdd(&scalars[2], s2p);          // S2 += ||c_p||^2
        atomicAdd(&scalars[1], cntf * s2p);   // S1 += cnt_p * ||c_p||^2
        float sq = 0.f;
        #pragma unroll
        for (int ww = 0; ww < MW; ++ww) sq += sred[ww];
        atomicAdd(&scalars[0], sq);           // SumSq
    }
}

extern "C" __global__ void __launch_bounds__(DIMS)
k_final(const float* __restrict__ T, const float* __restrict__ scalars,
        const int* __restrict__ nump, float* __restrict__ out)
{
    __shared__ float red[4];
    const int d = threadIdx.x;
    const float t = T[d];
    float tt = t * t;
    for (int off = 32; off; off >>= 1) tt += __shfl_down(tt, off, 64);
    if ((d & 63) == 0) red[d >> 6] = tt;
    __syncthreads();
    if (d == 0) {
        const double TT    = (double)red[0] + red[1] + red[2] + red[3];
        const double SumSq = (double)scalars[0];
        const double S1    = (double)scalars[1];
        const double S2    = (double)scalars[2];
        const double Pd    = (double)(*nump);
        const double within  = SumSq - S1;
        const double between = Pd * S2 - TT;
        const double pcsl = within / (between + 1e-6);
        const double gpal = S2 / Pd - TT / (Pd * Pd);
        out[0] = (float)(0.1 * pcsl + 0.1 * gpal);
    }
}

extern "C" void kernel_launch(void* const* d_in, const int* in_sizes, int n_in,
                              void* d_out, int out_size, void* d_ws, size_t ws_size,
                              hipStream_t stream)
{
    const float* feats = (const float*)d_in[0];
    const int*   pids  = (const int*)d_in[1];
    const int*   nump  = (const int*)d_in[2];
    float*       out   = (float*)d_out;

    const int N = in_sizes[0] / DIMS;

    char* ws = (char*)d_ws;
    unsigned* counts  = (unsigned*)(ws);
    unsigned* starts  = (unsigned*)(ws + 2048);
    float*    scalars = (float*)(ws + 4096);
    float*    T       = (float*)(ws + 4608);
    unsigned* bh      = (unsigned*)(ws + 8192);
    unsigned* idx     = (unsigned*)(ws + 139264);

    k_hist   <<<dim3(HB),   dim3(HT),   0, stream>>>(pids, N, bh);
    k_scan   <<<dim3(1),    dim3(NPAT), 0, stream>>>(bh, counts, starts,
                                                     scalars, T);
    k_scatter<<<dim3(HB),   dim3(HT),   0, stream>>>(pids, N, bh, starts, idx);
    k_main   <<<dim3(NPAT), dim3(MT),   0, stream>>>(feats, idx, counts, starts,
                                                     T, scalars);
    k_final  <<<dim3(1),    dim3(DIMS), 0, stream>>>(T, scalars, nump, out);
}